// Round 7
// baseline (156.002 us; speedup 1.0000x reference)
//
#include <hip/hip_runtime.h>
#include <hip/hip_fp16.h>
#include <float.h>

typedef _Float16 f16;
typedef __attribute__((ext_vector_type(4))) _Float16 f16x4;
typedef __attribute__((ext_vector_type(8))) _Float16 f16x8;
typedef __attribute__((ext_vector_type(4))) float f32x4;

#define NB 4
#define SEQ 1024
#define DIM 768
#define NH 12
#define HD 64
#define SCALE_F 0.125f
#define LOG2E 1.44269504088896f
#define NBH (NB * NH)          // 48
#define MASK_NEG (-1.0e30f)

// direct global->LDS DMA, 16B per lane (dest = wave-uniform base + lane*16)
__device__ __forceinline__ void gload16(const f16* g, f16* lds) {
    __builtin_amdgcn_global_load_lds(
        (const __attribute__((address_space(1))) void*)g,
        (__attribute__((address_space(3))) void*)lds, 16, 0, 0);
}

// ---------------------------------------------------------------------------
// Fused fp32->fp16 convert (X, w_qkv, w_proj) + mask bias build (last block).
// Mb[b*SEQ+n] = mask ? 0 : -1e30  (additive bias, log2-domain irrelevant).
// ---------------------------------------------------------------------------
__global__ __launch_bounds__(256) void cvt_mask_kernel(
    const float* __restrict__ X, const float* __restrict__ W1,
    const float* __restrict__ W2, const void* __restrict__ mask_raw,
    f16* __restrict__ Xh, f16* __restrict__ W1h, f16* __restrict__ W2h,
    float* __restrict__ Mb) {
    const int A4 = (NB * SEQ * DIM) / 4;
    const int B4 = (3 * DIM * DIM) / 4;
    const int C4 = (DIM * DIM) / 4;
    const int tid = threadIdx.x;
    if (blockIdx.x == (unsigned)(A4 + B4 + C4 + 255) / 256) {
        // mask block (verified): int32-or-uint8 autodetect
        __shared__ int is_u8;
        if (tid == 0) is_u8 = 0;
        __syncthreads();
        const unsigned int* u32 = (const unsigned int*)mask_raw;
        int bad = 0;
        for (int i = tid; i < (NB * SEQ) / 4; i += 256)
            if (u32[i] > 1u) bad = 1;
        if (bad) atomicOr(&is_u8, 1);
        __syncthreads();
        const int u8mode = is_u8;
        const unsigned char* u8 = (const unsigned char*)mask_raw;
        const int* i32 = (const int*)mask_raw;
        for (int i = tid; i < NB * SEQ; i += 256) {
            const int m = u8mode ? (u8[i] != 0) : (i32[i] != 0);
            Mb[i] = m ? 0.0f : MASK_NEG;
        }
        return;
    }
    int i = blockIdx.x * 256 + tid;
    const float* s; f16* d; int j;
    if (i < A4)                { s = X;  d = Xh;  j = i; }
    else if (i < A4 + B4)      { s = W1; d = W1h; j = i - A4; }
    else if (i < A4 + B4 + C4) { s = W2; d = W2h; j = i - A4 - B4; }
    else return;
    float4 v = ((const float4*)s)[j];
    f16x4 h;
    h[0] = (f16)v.x; h[1] = (f16)v.y; h[2] = (f16)v.z; h[3] = (f16)v.w;
    *(f16x4*)(d + 4 * (size_t)j) = h;
}

// ---------------------------------------------------------------------------
// QKV GEMM, fp16 MFMA 16x16x32, global_load_lds staging (m97 structure).
// Epilogue: Q (pre-scaled by SCALE*log2e for exp2 softmax), K -> [bh][n][d];
// V -> transposed [bh][d][n].
// ---------------------------------------------------------------------------
__global__ __launch_bounds__(256) void qkv_gemm_f16(
    const f16* __restrict__ Xh, const f16* __restrict__ Wh,
    f16* __restrict__ Qh, f16* __restrict__ Kh, f16* __restrict__ Vth) {
    __shared__ __align__(16) f16 Ah[128 * 32];
    __shared__ __align__(16) f16 Bh[128 * 32];
    const int tid = threadIdx.x;
    const int l = tid & 63, w = tid >> 6;
    const int lo = l & 15, hi = l >> 4;
    const int wm = w >> 1, wn = w & 1;
    const int m0 = blockIdx.y * 128, o0 = blockIdx.x * 128;

    f32x4 acc[4][4];
#pragma unroll
    for (int i = 0; i < 4; ++i)
#pragma unroll
        for (int j = 0; j < 4; ++j) { f32x4 z = {0.f, 0.f, 0.f, 0.f}; acc[i][j] = z; }

    const int gr = l >> 2;
    const int gc = (l & 3) * 8;
    const f16* gA = Xh + (size_t)(m0 + w * 32 + gr) * DIM + gc;
    const f16* gB = Wh + (size_t)(o0 + w * 32 + gr) * DIM + gc;
    f16* lA = Ah + (w * 2) * 512;
    f16* lB = Bh + (w * 2) * 512;

    for (int k0 = 0; k0 < DIM; k0 += 32) {
        __syncthreads();
        gload16(gA + k0,            lA);
        gload16(gA + k0 + 16 * DIM, lA + 512);
        gload16(gB + k0,            lB);
        gload16(gB + k0 + 16 * DIM, lB + 512);
        __syncthreads();
        f16x8 af[4], bf[4];
#pragma unroll
        for (int i = 0; i < 4; ++i)
            af[i] = *(const f16x8*)&Ah[(wm * 64 + i * 16 + lo) * 32 + hi * 8];
#pragma unroll
        for (int j = 0; j < 4; ++j)
            bf[j] = *(const f16x8*)&Bh[(wn * 64 + j * 16 + lo) * 32 + hi * 8];
#pragma unroll
        for (int i = 0; i < 4; ++i)
#pragma unroll
            for (int j = 0; j < 4; ++j)
                acc[i][j] = __builtin_amdgcn_mfma_f32_16x16x32_f16(af[i], bf[j], acc[i][j], 0, 0, 0);
    }

    const int oo = o0 + wn * 64;
    const int s = oo / DIM;
    const int hh = (oo % DIM) / HD;
    const int b = m0 >> 10;
    const int nbase = (m0 & 1023) + wm * 64;
    if (s < 2) {
        f16* dst = (s == 0) ? Qh : Kh;
        const float qs = (s == 0) ? SCALE_F * LOG2E : 1.0f;  // fold scale+log2e
        f16* base = dst + ((size_t)(b * NH + hh)) * SEQ * HD;
#pragma unroll
        for (int i = 0; i < 4; ++i)
#pragma unroll
            for (int r = 0; r < 4; ++r) {
                const int n = nbase + i * 16 + hi * 4 + r;
#pragma unroll
                for (int j = 0; j < 4; ++j)
                    base[(size_t)n * HD + j * 16 + lo] = (f16)(acc[i][j][r] * qs);
            }
    } else {
        f16* base = Vth + ((size_t)(b * NH + hh)) * HD * SEQ;
#pragma unroll
        for (int i = 0; i < 4; ++i) {
            const int n4 = nbase + i * 16 + hi * 4;
#pragma unroll
            for (int j = 0; j < 4; ++j) {
                const int d = j * 16 + lo;
                f16x4 pv;
#pragma unroll
                for (int r = 0; r < 4; ++r) pv[r] = (f16)acc[i][j][r];
                *(f16x4*)(base + (size_t)d * SEQ + n4) = pv;
            }
        }
    }
}

// ---------------------------------------------------------------------------
// Flash attention, BARRIER-FREE. One wave per block; each wave owns 16 q-rows
// and iterates 16 KV tiles. K/V fragments are read DIRECTLY from global
// (L1/L2-resident: 8 KB per tile, 256 KB per head) — no LDS staging, no
// __syncthreads (m169 precedent: staging L2-fit data is pure overhead).
// Swapped-QK^T: lane owns one q-row -> scalar exp2 softmax. Mask is an
// additive f32 bias (0 / -1e30); fully-masked rows -> all-0 scores ->
// uniform softmax over ALL kv (matches reference exactly).
// P goes through a wave-private 2 KB LDS buffer (XOR-swizzled, no barrier).
// ---------------------------------------------------------------------------
__global__ __launch_bounds__(64) void attn_f16(
    const f16* __restrict__ Qh, const f16* __restrict__ Kh,
    const f16* __restrict__ Vth, const float* __restrict__ Mb,
    f16* __restrict__ Oh) {
    const int bh = blockIdx.y, b = bh / NH, hh = bh % NH;
    const int q0 = blockIdx.x * 16;
    const int l = threadIdx.x;
    const int lo = l & 15, hi = l >> 4;

    __shared__ __align__(16) f16 Ps[16][64];   // wave-private P tile

    const f16* Qp = Qh + (size_t)bh * SEQ * HD;
    const f16* Kp = Kh + (size_t)bh * SEQ * HD;
    const f16* Vp = Vth + (size_t)bh * HD * SEQ;
    const float* Mbb = Mb + b * SEQ;

    // Q B-fragments (col = q-row = lo, k = d); Q pre-scaled by SCALE*log2e
    f16x8 qa[2];
#pragma unroll
    for (int kk = 0; kk < 2; ++kk)
        qa[kk] = *(const f16x8*)(Qp + (size_t)(q0 + lo) * HD + kk * 32 + hi * 8);
    const bool mq = (Mbb[q0 + lo] == 0.0f);

    float m_run = -FLT_MAX, l_run = 0.f;
    f32x4 oacc[4];
#pragma unroll
    for (int n = 0; n < 4; ++n) { f32x4 z = {0.f, 0.f, 0.f, 0.f}; oacc[n] = z; }

    const int s8 = (lo & 7) * 8;   // 16B-granule XOR for P buffer

    for (int t = 0; t < SEQ / 64; ++t) {
        const int kv0 = t * 64;
        // S^T = K Q^T : sf[f][r] = S[q-row lo][kv = f*16 + hi*4 + r]
        f32x4 sf[4];
#pragma unroll
        for (int f = 0; f < 4; ++f) { f32x4 z = {0.f, 0.f, 0.f, 0.f}; sf[f] = z; }
#pragma unroll
        for (int kk = 0; kk < 2; ++kk)
#pragma unroll
            for (int f = 0; f < 4; ++f) {
                f16x8 kf = *(const f16x8*)(Kp + (size_t)(kv0 + f * 16 + lo) * HD
                                              + kk * 32 + hi * 8);
                sf[f] = __builtin_amdgcn_mfma_f32_16x16x32_f16(kf, qa[kk], sf[f], 0, 0, 0);
            }
        // mask bias: masked kv -> -1e30; masked q-row -> all 0 (uniform)
#pragma unroll
        for (int f = 0; f < 4; ++f) {
            f32x4 bias = *(const f32x4*)(Mbb + kv0 + f * 16 + hi * 4);
#pragma unroll
            for (int r = 0; r < 4; ++r) {
                const float sv = sf[f][r] + bias[r];
                sf[f][r] = mq ? sv : 0.0f;
            }
        }
        // scalar online softmax (exp2) for this lane's q-row
        float pm = -FLT_MAX;
#pragma unroll
        for (int f = 0; f < 4; ++f)
            pm = fmaxf(pm, fmaxf(fmaxf(sf[f][0], sf[f][1]), fmaxf(sf[f][2], sf[f][3])));
        pm = fmaxf(pm, __shfl_xor(pm, 16));
        pm = fmaxf(pm, __shfl_xor(pm, 32));
        const float mn = fmaxf(m_run, pm);
        const float alpha = exp2f(m_run - mn);
        m_run = mn;
        float rs = 0.f;
#pragma unroll
        for (int f = 0; f < 4; ++f)
#pragma unroll
            for (int r = 0; r < 4; ++r) {
                float p = exp2f(sf[f][r] - mn);
                sf[f][r] = p;
                rs += p;
            }
        rs += __shfl_xor(rs, 16);
        rs += __shfl_xor(rs, 32);
        l_run = l_run * alpha + rs;

        // P -> wave-private LDS (b64 stores, conflict-free via XOR swizzle)
#pragma unroll
        for (int f = 0; f < 4; ++f) {
            f16x4 pv;
#pragma unroll
            for (int r = 0; r < 4; ++r) pv[r] = (f16)sf[f][r];
            *(f16x4*)&Ps[lo][(f * 16 + hi * 4) ^ s8] = pv;
        }
        // defer-skip: rescale only when some lane's max grew
        if (!__all(alpha == 1.0f)) {
            float ar[4];
#pragma unroll
            for (int r = 0; r < 4; ++r) ar[r] = __shfl(alpha, hi * 4 + r);
#pragma unroll
            for (int n = 0; n < 4; ++n)
#pragma unroll
                for (int r = 0; r < 4; ++r) oacc[n][r] *= ar[r];
        }
        // O += P V  (V fragments direct from global, transposed layout)
#pragma unroll
        for (int kk = 0; kk < 2; ++kk) {
            f16x8 pa = *(const f16x8*)&Ps[lo][(kk * 32 + hi * 8) ^ s8];
#pragma unroll
            for (int n = 0; n < 4; ++n) {
                f16x8 vb = *(const f16x8*)(Vp + (size_t)(n * 16 + lo) * SEQ
                                              + kv0 + kk * 32 + hi * 8);
                oacc[n] = __builtin_amdgcn_mfma_f32_16x16x32_f16(pa, vb, oacc[n], 0, 0, 0);
            }
        }
    }

    // epilogue: normalized O -> Oh [b][n][hh*64+d]
    float il[4];
#pragma unroll
    for (int r = 0; r < 4; ++r) il[r] = __shfl(l_run, hi * 4 + r);
    f16* Op = Oh + ((size_t)b * SEQ + q0) * DIM + hh * HD;
#pragma unroll
    for (int r = 0; r < 4; ++r) {
        const float inv = 1.f / il[r];
#pragma unroll
        for (int n = 0; n < 4; ++n)
            Op[(size_t)(hi * 4 + r) * DIM + n * 16 + lo] = (f16)(oacc[n][r] * inv);
    }
}

// ---------------------------------------------------------------------------
// Projection GEMM, fp16 MFMA, global_load_lds staging.
// ---------------------------------------------------------------------------
__global__ __launch_bounds__(256) void proj_gemm_f16(
    const f16* __restrict__ Oh, const f16* __restrict__ Wph,
    const float* __restrict__ bp, float* __restrict__ out) {
    __shared__ __align__(16) f16 Ah[128 * 32];
    __shared__ __align__(16) f16 Bh[128 * 32];
    const int tid = threadIdx.x;
    const int l = tid & 63, w = tid >> 6;
    const int lo = l & 15, hi = l >> 4;
    const int wm = w >> 1, wn = w & 1;
    const int m0 = blockIdx.y * 128, o0 = blockIdx.x * 128;

    f32x4 acc[4][4];
#pragma unroll
    for (int i = 0; i < 4; ++i)
#pragma unroll
        for (int j = 0; j < 4; ++j) { f32x4 z = {0.f, 0.f, 0.f, 0.f}; acc[i][j] = z; }

    const int gr = l >> 2;
    const int gc = (l & 3) * 8;
    const f16* gA = Oh + (size_t)(m0 + w * 32 + gr) * DIM + gc;
    const f16* gB = Wph + (size_t)(o0 + w * 32 + gr) * DIM + gc;
    f16* lA = Ah + (w * 2) * 512;
    f16* lB = Bh + (w * 2) * 512;

    for (int k0 = 0; k0 < DIM; k0 += 32) {
        __syncthreads();
        gload16(gA + k0,            lA);
        gload16(gA + k0 + 16 * DIM, lA + 512);
        gload16(gB + k0,            lB);
        gload16(gB + k0 + 16 * DIM, lB + 512);
        __syncthreads();
        f16x8 af[4], bf[4];
#pragma unroll
        for (int i = 0; i < 4; ++i)
            af[i] = *(const f16x8*)&Ah[(wm * 64 + i * 16 + lo) * 32 + hi * 8];
#pragma unroll
        for (int j = 0; j < 4; ++j)
            bf[j] = *(const f16x8*)&Bh[(wn * 64 + j * 16 + lo) * 32 + hi * 8];
#pragma unroll
        for (int i = 0; i < 4; ++i)
#pragma unroll
            for (int j = 0; j < 4; ++j)
                acc[i][j] = __builtin_amdgcn_mfma_f32_16x16x32_f16(af[i], bf[j], acc[i][j], 0, 0, 0);
    }

    float bpv[4];
#pragma unroll
    for (int j = 0; j < 4; ++j) bpv[j] = bp[o0 + wn * 64 + j * 16 + lo];
#pragma unroll
    for (int i = 0; i < 4; ++i)
#pragma unroll
        for (int r = 0; r < 4; ++r) {
            const int m = m0 + wm * 64 + i * 16 + hi * 4 + r;
#pragma unroll
            for (int j = 0; j < 4; ++j)
                out[(size_t)m * DIM + o0 + wn * 64 + j * 16 + lo] = acc[i][j][r] + bpv[j];
        }
}

// ---------------------------------------------------------------------------
extern "C" void kernel_launch(void* const* d_in, const int* in_sizes, int n_in,
                              void* d_out, int out_size, void* d_ws, size_t ws_size,
                              hipStream_t stream) {
    const float* x      = (const float*)d_in[0];
    const void*  mask   = d_in[1];
    const float* w_qkv  = (const float*)d_in[2];
    const float* w_proj = (const float*)d_in[3];
    const float* b_proj = (const float*)d_in[4];
    float* out          = (float*)d_out;

    char* w = (char*)d_ws;
    float* Mb = (float*)w;                 w += 16384;
    const size_t NX  = (size_t)NB * SEQ * DIM;
    const size_t NW1 = (size_t)3 * DIM * DIM;
    const size_t NW2 = (size_t)DIM * DIM;
    f16* Xh   = (f16*)w;  w += NX  * sizeof(f16);
    f16* W1h  = (f16*)w;  w += NW1 * sizeof(f16);
    f16* W2h  = (f16*)w;  w += NW2 * sizeof(f16);
    f16* Qh   = (f16*)w;  w += NX * sizeof(f16);
    f16* Kh   = (f16*)w;  w += NX * sizeof(f16);
    f16* Vth  = (f16*)w;  w += NX * sizeof(f16);
    f16* Oh   = (f16*)w;  w += NX * sizeof(f16);

    const int cvt_blocks = ((NB * SEQ * DIM + 4 * DIM * DIM) / 4 + 255) / 256 + 1;
    cvt_mask_kernel<<<cvt_blocks, 256, 0, stream>>>(x, w_qkv, w_proj, mask,
                                                    Xh, W1h, W2h, Mb);
    qkv_gemm_f16<<<dim3(18, 32), 256, 0, stream>>>(Xh, W1h, Qh, Kh, Vth);
    attn_f16<<<dim3(SEQ / 16, NBH), 64, 0, stream>>>(Qh, Kh, Vth, Mb, Oh);
    proj_gemm_f16<<<dim3(6, 32), 256, 0, stream>>>(Oh, W2h, b_proj, out);
}

// Round 8
// 109.010 us; speedup vs baseline: 1.4311x; 1.4311x over previous
//
#include <hip/hip_runtime.h>
#include <hip/hip_fp16.h>
#include <float.h>

typedef _Float16 f16;
typedef __attribute__((ext_vector_type(4))) _Float16 f16x4;
typedef __attribute__((ext_vector_type(8))) _Float16 f16x8;
typedef __attribute__((ext_vector_type(4))) float f32x4;

#define NB 4
#define SEQ 1024
#define DIM 768
#define NH 12
#define HD 64
#define SCALE_F 0.125f
#define LOG2E 1.44269504088896f
#define NBH (NB * NH)          // 48
#define MASK_NEG (-1.0e30f)

// direct global->LDS DMA, 16B per lane (dest = wave-uniform base + lane*16)
__device__ __forceinline__ void gload16(const f16* g, f16* lds) {
    __builtin_amdgcn_global_load_lds(
        (const __attribute__((address_space(1))) void*)g,
        (__attribute__((address_space(3))) void*)lds, 16, 0, 0);
}

// ---------------------------------------------------------------------------
// Fused fp32->fp16 convert (X, w_qkv, w_proj) + mask bias build (last block).
// Mb[b*SEQ+n] = mask ? 0 : -1e30  (additive bias).
// ---------------------------------------------------------------------------
__global__ __launch_bounds__(256) void cvt_mask_kernel(
    const float* __restrict__ X, const float* __restrict__ W1,
    const float* __restrict__ W2, const void* __restrict__ mask_raw,
    f16* __restrict__ Xh, f16* __restrict__ W1h, f16* __restrict__ W2h,
    float* __restrict__ Mb) {
    const int A4 = (NB * SEQ * DIM) / 4;
    const int B4 = (3 * DIM * DIM) / 4;
    const int C4 = (DIM * DIM) / 4;
    const int tid = threadIdx.x;
    if (blockIdx.x == (unsigned)(A4 + B4 + C4 + 255) / 256) {
        // mask block (verified): int32-or-uint8 autodetect
        __shared__ int is_u8;
        if (tid == 0) is_u8 = 0;
        __syncthreads();
        const unsigned int* u32 = (const unsigned int*)mask_raw;
        int bad = 0;
        for (int i = tid; i < (NB * SEQ) / 4; i += 256)
            if (u32[i] > 1u) bad = 1;
        if (bad) atomicOr(&is_u8, 1);
        __syncthreads();
        const int u8mode = is_u8;
        const unsigned char* u8 = (const unsigned char*)mask_raw;
        const int* i32 = (const int*)mask_raw;
        for (int i = tid; i < NB * SEQ; i += 256) {
            const int m = u8mode ? (u8[i] != 0) : (i32[i] != 0);
            Mb[i] = m ? 0.0f : MASK_NEG;
        }
        return;
    }
    int i = blockIdx.x * 256 + tid;
    const float* s; f16* d; int j;
    if (i < A4)                { s = X;  d = Xh;  j = i; }
    else if (i < A4 + B4)      { s = W1; d = W1h; j = i - A4; }
    else if (i < A4 + B4 + C4) { s = W2; d = W2h; j = i - A4 - B4; }
    else return;
    float4 v = ((const float4*)s)[j];
    f16x4 h;
    h[0] = (f16)v.x; h[1] = (f16)v.y; h[2] = (f16)v.z; h[3] = (f16)v.w;
    *(f16x4*)(d + 4 * (size_t)j) = h;
}

// ---------------------------------------------------------------------------
// QKV GEMM, fp16 MFMA 16x16x32, global_load_lds staging (m97 structure).
// Epilogue: Q (pre-scaled by SCALE*log2e for exp2 softmax), K -> [bh][n][d];
// V -> transposed [bh][d][n].
// ---------------------------------------------------------------------------
__global__ __launch_bounds__(256) void qkv_gemm_f16(
    const f16* __restrict__ Xh, const f16* __restrict__ Wh,
    f16* __restrict__ Qh, f16* __restrict__ Kh, f16* __restrict__ Vth) {
    __shared__ __align__(16) f16 Ah[128 * 32];
    __shared__ __align__(16) f16 Bh[128 * 32];
    const int tid = threadIdx.x;
    const int l = tid & 63, w = tid >> 6;
    const int lo = l & 15, hi = l >> 4;
    const int wm = w >> 1, wn = w & 1;
    const int m0 = blockIdx.y * 128, o0 = blockIdx.x * 128;

    f32x4 acc[4][4];
#pragma unroll
    for (int i = 0; i < 4; ++i)
#pragma unroll
        for (int j = 0; j < 4; ++j) { f32x4 z = {0.f, 0.f, 0.f, 0.f}; acc[i][j] = z; }

    const int gr = l >> 2;
    const int gc = (l & 3) * 8;
    const f16* gA = Xh + (size_t)(m0 + w * 32 + gr) * DIM + gc;
    const f16* gB = Wh + (size_t)(o0 + w * 32 + gr) * DIM + gc;
    f16* lA = Ah + (w * 2) * 512;
    f16* lB = Bh + (w * 2) * 512;

    for (int k0 = 0; k0 < DIM; k0 += 32) {
        __syncthreads();
        gload16(gA + k0,            lA);
        gload16(gA + k0 + 16 * DIM, lA + 512);
        gload16(gB + k0,            lB);
        gload16(gB + k0 + 16 * DIM, lB + 512);
        __syncthreads();
        f16x8 af[4], bf[4];
#pragma unroll
        for (int i = 0; i < 4; ++i)
            af[i] = *(const f16x8*)&Ah[(wm * 64 + i * 16 + lo) * 32 + hi * 8];
#pragma unroll
        for (int j = 0; j < 4; ++j)
            bf[j] = *(const f16x8*)&Bh[(wn * 64 + j * 16 + lo) * 32 + hi * 8];
#pragma unroll
        for (int i = 0; i < 4; ++i)
#pragma unroll
            for (int j = 0; j < 4; ++j)
                acc[i][j] = __builtin_amdgcn_mfma_f32_16x16x32_f16(af[i], bf[j], acc[i][j], 0, 0, 0);
    }

    const int oo = o0 + wn * 64;
    const int s = oo / DIM;
    const int hh = (oo % DIM) / HD;
    const int b = m0 >> 10;
    const int nbase = (m0 & 1023) + wm * 64;
    if (s < 2) {
        f16* dst = (s == 0) ? Qh : Kh;
        const float qs = (s == 0) ? SCALE_F * LOG2E : 1.0f;
        f16* base = dst + ((size_t)(b * NH + hh)) * SEQ * HD;
#pragma unroll
        for (int i = 0; i < 4; ++i)
#pragma unroll
            for (int r = 0; r < 4; ++r) {
                const int n = nbase + i * 16 + hi * 4 + r;
#pragma unroll
                for (int j = 0; j < 4; ++j)
                    base[(size_t)n * HD + j * 16 + lo] = (f16)(acc[i][j][r] * qs);
            }
    } else {
        f16* base = Vth + ((size_t)(b * NH + hh)) * HD * SEQ;
#pragma unroll
        for (int i = 0; i < 4; ++i) {
            const int n4 = nbase + i * 16 + hi * 4;
#pragma unroll
            for (int j = 0; j < 4; ++j) {
                const int d = j * 16 + lo;
                f16x4 pv;
#pragma unroll
                for (int r = 0; r < 4; ++r) pv[r] = (f16)acc[i][j][r];
                *(f16x4*)(base + (size_t)d * SEQ + n4) = pv;
            }
        }
    }
}

// ---------------------------------------------------------------------------
// Flash attention, q-blocked: 2 waves/block, each wave owns 32 q-rows
// (2 groups of 16). K/V staged in LDS per tile and each fragment read feeds
// 2 MFMAs (one per q-group) -> DS-ops-per-MFMA ~1.1 (was 1.6).
// Swapped-QK^T (lane owns one q-row per group -> scalar exp2 softmax).
// LDS [64][64] linear + 16B-granule XOR swizzle (verified conflict-free).
// T14 async staging via register prefetch. Mask = additive f32 bias.
// ---------------------------------------------------------------------------
__global__ __launch_bounds__(128) void attn_f16(
    const f16* __restrict__ Qh, const f16* __restrict__ Kh,
    const f16* __restrict__ Vth, const float* __restrict__ Mb,
    f16* __restrict__ Oh) {
    const int bh = blockIdx.y, b = bh / NH, hh = bh % NH;
    const int q0 = blockIdx.x * 64;
    const int tid = threadIdx.x;
    const int l = tid & 63, w = tid >> 6;
    const int lo = l & 15, hi = l >> 4;

    __shared__ __align__(16) f16 Ks[64][64];        // [kv][d], XOR-swizzled
    __shared__ __align__(16) f16 Vs[64][64];        // [d][kv], XOR-swizzled
    __shared__ __align__(16) f16 Ps[2][2][16][64];  // [wave][grp][qr][kv]

    const f16* Qp = Qh + (size_t)bh * SEQ * HD;
    const f16* Kp = Kh + (size_t)bh * SEQ * HD;
    const f16* Vp = Vth + (size_t)bh * HD * SEQ;
    const float* Mbb = Mb + b * SEQ;

    // Q B-fragments for both groups (pre-scaled by SCALE*log2e)
    f16x8 qa[2][2];
    bool mq[2];
#pragma unroll
    for (int g = 0; g < 2; ++g) {
        const int qrow = q0 + w * 32 + g * 16 + lo;
#pragma unroll
        for (int kk = 0; kk < 2; ++kk)
            qa[g][kk] = *(const f16x8*)(Qp + (size_t)qrow * HD + kk * 32 + hi * 8);
        mq[g] = (Mbb[qrow] == 0.0f);
    }

    float m_run[2] = {-FLT_MAX, -FLT_MAX}, l_run[2] = {0.f, 0.f};
    f32x4 oacc[2][4];
#pragma unroll
    for (int g = 0; g < 2; ++g)
#pragma unroll
        for (int n = 0; n < 4; ++n) { f32x4 z = {0.f, 0.f, 0.f, 0.f}; oacc[g][n] = z; }

    // staging: 128 lanes, 2 lanes/row, 64B (4x16B) per lane per tensor
    const int sr = tid >> 1, e = tid & 1;
    const int swz = (sr & 7) * 8;        // granule16 XOR for staging row sr
    const int s8 = (lo & 7) * 8;         // granule16 XOR for frag rows

    f16x8 kr[4], vr[4];
#pragma unroll
    for (int i = 0; i < 4; ++i) {
        kr[i] = *(const f16x8*)(Kp + (size_t)sr * HD + e * 32 + i * 8);
        vr[i] = *(const f16x8*)(Vp + (size_t)sr * SEQ + e * 32 + i * 8);
    }

    for (int t = 0; t < SEQ / 64; ++t) {
        const int kv0 = t * 64;
        __syncthreads();
#pragma unroll
        for (int i = 0; i < 4; ++i) {
            *(f16x8*)&Ks[sr][(e * 32 + i * 8) ^ swz] = kr[i];
            *(f16x8*)&Vs[sr][(e * 32 + i * 8) ^ swz] = vr[i];
        }
        __syncthreads();
        if (t < SEQ / 64 - 1) {   // T14: issue next tile's loads now
            const int kv1 = kv0 + 64;
#pragma unroll
            for (int i = 0; i < 4; ++i) {
                kr[i] = *(const f16x8*)(Kp + (size_t)(kv1 + sr) * HD + e * 32 + i * 8);
                vr[i] = *(const f16x8*)(Vp + (size_t)sr * SEQ + kv1 + e * 32 + i * 8);
            }
        }

        // S^T = K Q^T for BOTH groups: each kf read feeds 2 MFMAs
        f32x4 sf[2][4];
#pragma unroll
        for (int g = 0; g < 2; ++g)
#pragma unroll
            for (int f = 0; f < 4; ++f) { f32x4 z = {0.f, 0.f, 0.f, 0.f}; sf[g][f] = z; }
#pragma unroll
        for (int kk = 0; kk < 2; ++kk)
#pragma unroll
            for (int f = 0; f < 4; ++f) {
                f16x8 kf = *(const f16x8*)&Ks[f * 16 + lo][(kk * 32 + hi * 8) ^ s8];
                sf[0][f] = __builtin_amdgcn_mfma_f32_16x16x32_f16(kf, qa[0][kk], sf[0][f], 0, 0, 0);
                sf[1][f] = __builtin_amdgcn_mfma_f32_16x16x32_f16(kf, qa[1][kk], sf[1][f], 0, 0, 0);
            }

        // mask bias (per kv, shared by groups) + softmax per group
        f32x4 bias[4];
#pragma unroll
        for (int f = 0; f < 4; ++f)
            bias[f] = *(const f32x4*)(Mbb + kv0 + f * 16 + hi * 4);

        float alpha[2];
#pragma unroll
        for (int g = 0; g < 2; ++g) {
#pragma unroll
            for (int f = 0; f < 4; ++f)
#pragma unroll
                for (int r = 0; r < 4; ++r) {
                    const float sv = sf[g][f][r] + bias[f][r];
                    sf[g][f][r] = mq[g] ? sv : 0.0f;
                }
            float pm = -FLT_MAX;
#pragma unroll
            for (int f = 0; f < 4; ++f)
                pm = fmaxf(pm, fmaxf(fmaxf(sf[g][f][0], sf[g][f][1]),
                                     fmaxf(sf[g][f][2], sf[g][f][3])));
            pm = fmaxf(pm, __shfl_xor(pm, 16));
            pm = fmaxf(pm, __shfl_xor(pm, 32));
            const float mn = fmaxf(m_run[g], pm);
            alpha[g] = exp2f(m_run[g] - mn);
            m_run[g] = mn;
            float rs = 0.f;
#pragma unroll
            for (int f = 0; f < 4; ++f)
#pragma unroll
                for (int r = 0; r < 4; ++r) {
                    float p = exp2f(sf[g][f][r] - mn);
                    sf[g][f][r] = p;
                    rs += p;
                }
            rs += __shfl_xor(rs, 16);
            rs += __shfl_xor(rs, 32);
            l_run[g] = l_run[g] * alpha[g] + rs;

            // P-store (b64, conflict-free)
#pragma unroll
            for (int f = 0; f < 4; ++f) {
                f16x4 pv;
#pragma unroll
                for (int r = 0; r < 4; ++r) pv[r] = (f16)sf[g][f][r];
                *(f16x4*)&Ps[w][g][lo][(f * 16 + hi * 4) ^ s8] = pv;
            }
            // defer-skip rescale
            if (!__all(alpha[g] == 1.0f)) {
                float ar[4];
#pragma unroll
                for (int r = 0; r < 4; ++r) ar[r] = __shfl(alpha[g], hi * 4 + r);
#pragma unroll
                for (int n = 0; n < 4; ++n)
#pragma unroll
                    for (int r = 0; r < 4; ++r) oacc[g][n][r] *= ar[r];
            }
        }

        // O += P V : each vb read feeds 2 MFMAs
#pragma unroll
        for (int kk = 0; kk < 2; ++kk) {
            f16x8 pa0 = *(const f16x8*)&Ps[w][0][lo][(kk * 32 + hi * 8) ^ s8];
            f16x8 pa1 = *(const f16x8*)&Ps[w][1][lo][(kk * 32 + hi * 8) ^ s8];
#pragma unroll
            for (int n = 0; n < 4; ++n) {
                f16x8 vb = *(const f16x8*)&Vs[n * 16 + lo][(kk * 32 + hi * 8) ^ s8];
                oacc[0][n] = __builtin_amdgcn_mfma_f32_16x16x32_f16(pa0, vb, oacc[0][n], 0, 0, 0);
                oacc[1][n] = __builtin_amdgcn_mfma_f32_16x16x32_f16(pa1, vb, oacc[1][n], 0, 0, 0);
            }
        }
    }

    // epilogue: normalized O -> Oh [b][n][hh*64+d]
#pragma unroll
    for (int g = 0; g < 2; ++g) {
        float il[4];
#pragma unroll
        for (int r = 0; r < 4; ++r) il[r] = __shfl(l_run[g], hi * 4 + r);
        f16* Op = Oh + ((size_t)b * SEQ + q0 + w * 32 + g * 16) * DIM + hh * HD;
#pragma unroll
        for (int r = 0; r < 4; ++r) {
            const float inv = 1.f / il[r];
#pragma unroll
            for (int n = 0; n < 4; ++n)
                Op[(size_t)(hi * 4 + r) * DIM + n * 16 + lo] = (f16)(oacc[g][n][r] * inv);
        }
    }
}

// ---------------------------------------------------------------------------
// Projection GEMM, fp16 MFMA, global_load_lds staging.
// ---------------------------------------------------------------------------
__global__ __launch_bounds__(256) void proj_gemm_f16(
    const f16* __restrict__ Oh, const f16* __restrict__ Wph,
    const float* __restrict__ bp, float* __restrict__ out) {
    __shared__ __align__(16) f16 Ah[128 * 32];
    __shared__ __align__(16) f16 Bh[128 * 32];
    const int tid = threadIdx.x;
    const int l = tid & 63, w = tid >> 6;
    const int lo = l & 15, hi = l >> 4;
    const int wm = w >> 1, wn = w & 1;
    const int m0 = blockIdx.y * 128, o0 = blockIdx.x * 128;

    f32x4 acc[4][4];
#pragma unroll
    for (int i = 0; i < 4; ++i)
#pragma unroll
        for (int j = 0; j < 4; ++j) { f32x4 z = {0.f, 0.f, 0.f, 0.f}; acc[i][j] = z; }

    const int gr = l >> 2;
    const int gc = (l & 3) * 8;
    const f16* gA = Oh + (size_t)(m0 + w * 32 + gr) * DIM + gc;
    const f16* gB = Wph + (size_t)(o0 + w * 32 + gr) * DIM + gc;
    f16* lA = Ah + (w * 2) * 512;
    f16* lB = Bh + (w * 2) * 512;

    for (int k0 = 0; k0 < DIM; k0 += 32) {
        __syncthreads();
        gload16(gA + k0,            lA);
        gload16(gA + k0 + 16 * DIM, lA + 512);
        gload16(gB + k0,            lB);
        gload16(gB + k0 + 16 * DIM, lB + 512);
        __syncthreads();
        f16x8 af[4], bf[4];
#pragma unroll
        for (int i = 0; i < 4; ++i)
            af[i] = *(const f16x8*)&Ah[(wm * 64 + i * 16 + lo) * 32 + hi * 8];
#pragma unroll
        for (int j = 0; j < 4; ++j)
            bf[j] = *(const f16x8*)&Bh[(wn * 64 + j * 16 + lo) * 32 + hi * 8];
#pragma unroll
        for (int i = 0; i < 4; ++i)
#pragma unroll
            for (int j = 0; j < 4; ++j)
                acc[i][j] = __builtin_amdgcn_mfma_f32_16x16x32_f16(af[i], bf[j], acc[i][j], 0, 0, 0);
    }

    float bpv[4];
#pragma unroll
    for (int j = 0; j < 4; ++j) bpv[j] = bp[o0 + wn * 64 + j * 16 + lo];
#pragma unroll
    for (int i = 0; i < 4; ++i)
#pragma unroll
        for (int r = 0; r < 4; ++r) {
            const int m = m0 + wm * 64 + i * 16 + hi * 4 + r;
#pragma unroll
            for (int j = 0; j < 4; ++j)
                out[(size_t)m * DIM + o0 + wn * 64 + j * 16 + lo] = acc[i][j][r] + bpv[j];
        }
}

// ---------------------------------------------------------------------------
extern "C" void kernel_launch(void* const* d_in, const int* in_sizes, int n_in,
                              void* d_out, int out_size, void* d_ws, size_t ws_size,
                              hipStream_t stream) {
    const float* x      = (const float*)d_in[0];
    const void*  mask   = d_in[1];
    const float* w_qkv  = (const float*)d_in[2];
    const float* w_proj = (const float*)d_in[3];
    const float* b_proj = (const float*)d_in[4];
    float* out          = (float*)d_out;

    char* w = (char*)d_ws;
    float* Mb = (float*)w;                 w += 16384;
    const size_t NX  = (size_t)NB * SEQ * DIM;
    const size_t NW1 = (size_t)3 * DIM * DIM;
    const size_t NW2 = (size_t)DIM * DIM;
    f16* Xh   = (f16*)w;  w += NX  * sizeof(f16);
    f16* W1h  = (f16*)w;  w += NW1 * sizeof(f16);
    f16* W2h  = (f16*)w;  w += NW2 * sizeof(f16);
    f16* Qh   = (f16*)w;  w += NX * sizeof(f16);
    f16* Kh   = (f16*)w;  w += NX * sizeof(f16);
    f16* Vth  = (f16*)w;  w += NX * sizeof(f16);
    f16* Oh   = (f16*)w;  w += NX * sizeof(f16);

    const int cvt_blocks = ((NB * SEQ * DIM + 4 * DIM * DIM) / 4 + 255) / 256 + 1;
    cvt_mask_kernel<<<cvt_blocks, 256, 0, stream>>>(x, w_qkv, w_proj, mask,
                                                    Xh, W1h, W2h, Mb);
    qkv_gemm_f16<<<dim3(18, 32), 256, 0, stream>>>(Xh, W1h, Qh, Kh, Vth);
    attn_f16<<<dim3(SEQ / 64, NBH), 128, 0, stream>>>(Qh, Kh, Vth, Mb, Oh);
    proj_gemm_f16<<<dim3(6, 32), 256, 0, stream>>>(Oh, W2h, b_proj, out);
}

// Round 9
// 97.105 us; speedup vs baseline: 1.6065x; 1.1226x over previous
//
#include <hip/hip_runtime.h>
#include <hip/hip_fp16.h>
#include <float.h>

typedef _Float16 f16;
typedef __attribute__((ext_vector_type(4))) _Float16 f16x4;
typedef __attribute__((ext_vector_type(8))) _Float16 f16x8;
typedef __attribute__((ext_vector_type(4))) float f32x4;

#define NB 4
#define SEQ 1024
#define DIM 768
#define NH 12
#define HD 64
#define SCALE_F 0.125f
#define LOG2E 1.44269504088896f
#define NBH (NB * NH)          // 48
#define MASK_NEG (-1.0e30f)

// direct global->LDS DMA, 16B per lane (dest = wave-uniform base + lane*16)
__device__ __forceinline__ void gload16(const f16* g, f16* lds) {
    __builtin_amdgcn_global_load_lds(
        (const __attribute__((address_space(1))) void*)g,
        (__attribute__((address_space(3))) void*)lds, 16, 0, 0);
}

// ---------------------------------------------------------------------------
// Fused fp32->fp16 convert (X, w_qkv, w_proj) + mask bias build (last block).
// Mb[b*SEQ+n] = mask ? 0 : -1e30  (additive bias).
// ---------------------------------------------------------------------------
__global__ __launch_bounds__(256) void cvt_mask_kernel(
    const float* __restrict__ X, const float* __restrict__ W1,
    const float* __restrict__ W2, const void* __restrict__ mask_raw,
    f16* __restrict__ Xh, f16* __restrict__ W1h, f16* __restrict__ W2h,
    float* __restrict__ Mb) {
    const int A4 = (NB * SEQ * DIM) / 4;
    const int B4 = (3 * DIM * DIM) / 4;
    const int C4 = (DIM * DIM) / 4;
    const int tid = threadIdx.x;
    if (blockIdx.x == (unsigned)(A4 + B4 + C4 + 255) / 256) {
        // mask block (verified): int32-or-uint8 autodetect
        __shared__ int is_u8;
        if (tid == 0) is_u8 = 0;
        __syncthreads();
        const unsigned int* u32 = (const unsigned int*)mask_raw;
        int bad = 0;
        for (int i = tid; i < (NB * SEQ) / 4; i += 256)
            if (u32[i] > 1u) bad = 1;
        if (bad) atomicOr(&is_u8, 1);
        __syncthreads();
        const int u8mode = is_u8;
        const unsigned char* u8 = (const unsigned char*)mask_raw;
        const int* i32 = (const int*)mask_raw;
        for (int i = tid; i < NB * SEQ; i += 256) {
            const int m = u8mode ? (u8[i] != 0) : (i32[i] != 0);
            Mb[i] = m ? 0.0f : MASK_NEG;
        }
        return;
    }
    int i = blockIdx.x * 256 + tid;
    const float* s; f16* d; int j;
    if (i < A4)                { s = X;  d = Xh;  j = i; }
    else if (i < A4 + B4)      { s = W1; d = W1h; j = i - A4; }
    else if (i < A4 + B4 + C4) { s = W2; d = W2h; j = i - A4 - B4; }
    else return;
    float4 v = ((const float4*)s)[j];
    f16x4 h;
    h[0] = (f16)v.x; h[1] = (f16)v.y; h[2] = (f16)v.z; h[3] = (f16)v.w;
    *(f16x4*)(d + 4 * (size_t)j) = h;
}

// ---------------------------------------------------------------------------
// QKV GEMM, fp16 MFMA 16x16x32, DOUBLE-BUFFERED global_load_lds staging
// (T3 minimum 2-phase: STAGE(k+1) issued before compute(k), 1 barrier/step).
// Epilogue: Q (pre-scaled by SCALE*log2e), K -> [bh][n][d]; V -> [bh][d][n].
// ---------------------------------------------------------------------------
__global__ __launch_bounds__(256) void qkv_gemm_f16(
    const f16* __restrict__ Xh, const f16* __restrict__ Wh,
    f16* __restrict__ Qh, f16* __restrict__ Kh, f16* __restrict__ Vth) {
    __shared__ __align__(16) f16 Ah[2][128 * 32];
    __shared__ __align__(16) f16 Bh[2][128 * 32];
    const int tid = threadIdx.x;
    const int l = tid & 63, w = tid >> 6;
    const int lo = l & 15, hi = l >> 4;
    const int wm = w >> 1, wn = w & 1;
    const int m0 = blockIdx.y * 128, o0 = blockIdx.x * 128;

    f32x4 acc[4][4];
#pragma unroll
    for (int i = 0; i < 4; ++i)
#pragma unroll
        for (int j = 0; j < 4; ++j) { f32x4 z = {0.f, 0.f, 0.f, 0.f}; acc[i][j] = z; }

    const int gr = l >> 2;
    const int gc = (l & 3) * 8;
    const f16* gA = Xh + (size_t)(m0 + w * 32 + gr) * DIM + gc;
    const f16* gB = Wh + (size_t)(o0 + w * 32 + gr) * DIM + gc;
    const int lofs = (w * 2) * 512;

    // prologue: stage k0=0 into buf0
    gload16(gA,            Ah[0] + lofs);
    gload16(gA + 16 * DIM, Ah[0] + lofs + 512);
    gload16(gB,            Bh[0] + lofs);
    gload16(gB + 16 * DIM, Bh[0] + lofs + 512);
    __syncthreads();

    int cur = 0;
    for (int k0 = 0; k0 < DIM; k0 += 32) {
        if (k0 + 32 < DIM) {   // STAGE next K-step before compute
            gload16(gA + k0 + 32,            Ah[cur ^ 1] + lofs);
            gload16(gA + k0 + 32 + 16 * DIM, Ah[cur ^ 1] + lofs + 512);
            gload16(gB + k0 + 32,            Bh[cur ^ 1] + lofs);
            gload16(gB + k0 + 32 + 16 * DIM, Bh[cur ^ 1] + lofs + 512);
        }
        f16x8 af[4], bf[4];
#pragma unroll
        for (int i = 0; i < 4; ++i)
            af[i] = *(const f16x8*)&Ah[cur][(wm * 64 + i * 16 + lo) * 32 + hi * 8];
#pragma unroll
        for (int j = 0; j < 4; ++j)
            bf[j] = *(const f16x8*)&Bh[cur][(wn * 64 + j * 16 + lo) * 32 + hi * 8];
#pragma unroll
        for (int i = 0; i < 4; ++i)
#pragma unroll
            for (int j = 0; j < 4; ++j)
                acc[i][j] = __builtin_amdgcn_mfma_f32_16x16x32_f16(af[i], bf[j], acc[i][j], 0, 0, 0);
        __syncthreads();
        cur ^= 1;
    }

    const int oo = o0 + wn * 64;
    const int s = oo / DIM;
    const int hh = (oo % DIM) / HD;
    const int b = m0 >> 10;
    const int nbase = (m0 & 1023) + wm * 64;
    if (s < 2) {
        f16* dst = (s == 0) ? Qh : Kh;
        const float qs = (s == 0) ? SCALE_F * LOG2E : 1.0f;
        f16* base = dst + ((size_t)(b * NH + hh)) * SEQ * HD;
#pragma unroll
        for (int i = 0; i < 4; ++i)
#pragma unroll
            for (int r = 0; r < 4; ++r) {
                const int n = nbase + i * 16 + hi * 4 + r;
#pragma unroll
                for (int j = 0; j < 4; ++j)
                    base[(size_t)n * HD + j * 16 + lo] = (f16)(acc[i][j][r] * qs);
            }
    } else {
        f16* base = Vth + ((size_t)(b * NH + hh)) * HD * SEQ;
#pragma unroll
        for (int i = 0; i < 4; ++i) {
            const int n4 = nbase + i * 16 + hi * 4;
#pragma unroll
            for (int j = 0; j < 4; ++j) {
                const int d = j * 16 + lo;
                f16x4 pv;
#pragma unroll
                for (int r = 0; r < 4; ++r) pv[r] = (f16)acc[i][j][r];
                *(f16x4*)(base + (size_t)d * SEQ + n4) = pv;
            }
        }
    }
}

// ---------------------------------------------------------------------------
// Flash attention: 4 waves/block, 64 q-rows, r6 structure + DOUBLE-BUFFERED
// K/V LDS -> ONE barrier per tile. Per tile: QK(buf cur) -> ds_write next
// tile(buf cur^1) -> global prefetch t+2 -> softmax -> PV(buf cur) -> barrier.
// Swapped-QK^T (lane owns one q-row, scalar exp2 softmax), XOR-swizzled LDS
// (verified conflict-free), mask = additive f32 bias, defer-skip rescale.
// ---------------------------------------------------------------------------
__global__ __launch_bounds__(256) void attn_f16(
    const f16* __restrict__ Qh, const f16* __restrict__ Kh,
    const f16* __restrict__ Vth, const float* __restrict__ Mb,
    f16* __restrict__ Oh) {
    const int bh = blockIdx.y, b = bh / NH, hh = bh % NH;
    const int q0 = blockIdx.x * 64;
    const int tid = threadIdx.x;
    const int l = tid & 63, w = tid >> 6;
    const int lo = l & 15, hi = l >> 4;

    __shared__ __align__(16) f16 Ks[2][64][64];     // [buf][kv][d], swizzled
    __shared__ __align__(16) f16 Vs[2][64][64];     // [buf][d][kv], swizzled
    __shared__ __align__(16) f16 Ps[4][16][64];     // per-wave [qr][kv]

    const f16* Qp = Qh + (size_t)bh * SEQ * HD;
    const f16* Kp = Kh + (size_t)bh * SEQ * HD;
    const f16* Vp = Vth + (size_t)bh * HD * SEQ;
    const float* Mbb = Mb + b * SEQ;

    f16x8 qa[2];
#pragma unroll
    for (int kk = 0; kk < 2; ++kk)
        qa[kk] = *(const f16x8*)(Qp + (size_t)(q0 + w * 16 + lo) * HD + kk * 32 + hi * 8);
    const bool mq = (Mbb[q0 + w * 16 + lo] == 0.0f);

    float m_run = -FLT_MAX, l_run = 0.f;
    f32x4 oacc[4];
#pragma unroll
    for (int n = 0; n < 4; ++n) { f32x4 z = {0.f, 0.f, 0.f, 0.f}; oacc[n] = z; }

    const int sr = tid >> 2, sc = (tid & 3) * 16;
    const int swz = (sr & 7) * 8;
    const int s8 = (lo & 7) * 8;

    // prologue: tile 0 -> buf0; prefetch tile 1 into regs
    f16x8 kr0, kr1, vr0, vr1;
    kr0 = *(const f16x8*)(Kp + (size_t)sr * HD + sc);
    kr1 = *(const f16x8*)(Kp + (size_t)sr * HD + sc + 8);
    vr0 = *(const f16x8*)(Vp + (size_t)sr * SEQ + sc);
    vr1 = *(const f16x8*)(Vp + (size_t)sr * SEQ + sc + 8);
    *(f16x8*)&Ks[0][sr][sc ^ swz]       = kr0;
    *(f16x8*)&Ks[0][sr][(sc + 8) ^ swz] = kr1;
    *(f16x8*)&Vs[0][sr][sc ^ swz]       = vr0;
    *(f16x8*)&Vs[0][sr][(sc + 8) ^ swz] = vr1;
    kr0 = *(const f16x8*)(Kp + (size_t)(64 + sr) * HD + sc);
    kr1 = *(const f16x8*)(Kp + (size_t)(64 + sr) * HD + sc + 8);
    vr0 = *(const f16x8*)(Vp + (size_t)sr * SEQ + 64 + sc);
    vr1 = *(const f16x8*)(Vp + (size_t)sr * SEQ + 64 + sc + 8);
    __syncthreads();

    int cur = 0;
    for (int t = 0; t < SEQ / 64; ++t) {
        const int kv0 = t * 64;
        // S^T = K Q^T from Ks[cur]
        f32x4 sf[4];
#pragma unroll
        for (int f = 0; f < 4; ++f) { f32x4 z = {0.f, 0.f, 0.f, 0.f}; sf[f] = z; }
#pragma unroll
        for (int kk = 0; kk < 2; ++kk)
#pragma unroll
            for (int f = 0; f < 4; ++f) {
                f16x8 kf = *(const f16x8*)&Ks[cur][f * 16 + lo][(kk * 32 + hi * 8) ^ s8];
                sf[f] = __builtin_amdgcn_mfma_f32_16x16x32_f16(kf, qa[kk], sf[f], 0, 0, 0);
            }
        // stage next tile into buf^1 (safe: last readers of buf^1 finished
        // before the previous barrier), then prefetch t+2 into regs
        if (t < SEQ / 64 - 1) {
            *(f16x8*)&Ks[cur ^ 1][sr][sc ^ swz]       = kr0;
            *(f16x8*)&Ks[cur ^ 1][sr][(sc + 8) ^ swz] = kr1;
            *(f16x8*)&Vs[cur ^ 1][sr][sc ^ swz]       = vr0;
            *(f16x8*)&Vs[cur ^ 1][sr][(sc + 8) ^ swz] = vr1;
            if (t < SEQ / 64 - 2) {
                const int kv2 = kv0 + 128;
                kr0 = *(const f16x8*)(Kp + (size_t)(kv2 + sr) * HD + sc);
                kr1 = *(const f16x8*)(Kp + (size_t)(kv2 + sr) * HD + sc + 8);
                vr0 = *(const f16x8*)(Vp + (size_t)sr * SEQ + kv2 + sc);
                vr1 = *(const f16x8*)(Vp + (size_t)sr * SEQ + kv2 + sc + 8);
            }
        }
        // mask bias + scalar online softmax (exp2)
        f32x4 bias[4];
#pragma unroll
        for (int f = 0; f < 4; ++f)
            bias[f] = *(const f32x4*)(Mbb + kv0 + f * 16 + hi * 4);
#pragma unroll
        for (int f = 0; f < 4; ++f)
#pragma unroll
            for (int r = 0; r < 4; ++r) {
                const float sv = sf[f][r] + bias[f][r];
                sf[f][r] = mq ? sv : 0.0f;
            }
        float pm = -FLT_MAX;
#pragma unroll
        for (int f = 0; f < 4; ++f)
            pm = fmaxf(pm, fmaxf(fmaxf(sf[f][0], sf[f][1]), fmaxf(sf[f][2], sf[f][3])));
        pm = fmaxf(pm, __shfl_xor(pm, 16));
        pm = fmaxf(pm, __shfl_xor(pm, 32));
        const float mn = fmaxf(m_run, pm);
        const float alpha = exp2f(m_run - mn);
        m_run = mn;
        float rs = 0.f;
#pragma unroll
        for (int f = 0; f < 4; ++f)
#pragma unroll
            for (int r = 0; r < 4; ++r) {
                float p = exp2f(sf[f][r] - mn);
                sf[f][r] = p;
                rs += p;
            }
        rs += __shfl_xor(rs, 16);
        rs += __shfl_xor(rs, 32);
        l_run = l_run * alpha + rs;

        // P-store (wave-private, b64, conflict-free)
#pragma unroll
        for (int f = 0; f < 4; ++f) {
            f16x4 pv;
#pragma unroll
            for (int r = 0; r < 4; ++r) pv[r] = (f16)sf[f][r];
            *(f16x4*)&Ps[w][lo][(f * 16 + hi * 4) ^ s8] = pv;
        }
        // defer-skip rescale
        if (!__all(alpha == 1.0f)) {
            float ar[4];
#pragma unroll
            for (int r = 0; r < 4; ++r) ar[r] = __shfl(alpha, hi * 4 + r);
#pragma unroll
            for (int n = 0; n < 4; ++n)
#pragma unroll
                for (int r = 0; r < 4; ++r) oacc[n][r] *= ar[r];
        }
        // O += P V from Vs[cur]
#pragma unroll
        for (int kk = 0; kk < 2; ++kk) {
            f16x8 pa = *(const f16x8*)&Ps[w][lo][(kk * 32 + hi * 8) ^ s8];
#pragma unroll
            for (int n = 0; n < 4; ++n) {
                f16x8 vb = *(const f16x8*)&Vs[cur][n * 16 + lo][(kk * 32 + hi * 8) ^ s8];
                oacc[n] = __builtin_amdgcn_mfma_f32_16x16x32_f16(pa, vb, oacc[n], 0, 0, 0);
            }
        }
        __syncthreads();
        cur ^= 1;
    }

    // epilogue: normalized O -> Oh [b][n][hh*64+d]
    float il[4];
#pragma unroll
    for (int r = 0; r < 4; ++r) il[r] = __shfl(l_run, hi * 4 + r);
    f16* Op = Oh + ((size_t)b * SEQ + q0 + w * 16) * DIM + hh * HD;
#pragma unroll
    for (int r = 0; r < 4; ++r) {
        const float inv = 1.f / il[r];
#pragma unroll
        for (int n = 0; n < 4; ++n)
            Op[(size_t)(hi * 4 + r) * DIM + n * 16 + lo] = (f16)(oacc[n][r] * inv);
    }
}

// ---------------------------------------------------------------------------
// Projection GEMM, fp16 MFMA, double-buffered global_load_lds staging.
// ---------------------------------------------------------------------------
__global__ __launch_bounds__(256) void proj_gemm_f16(
    const f16* __restrict__ Oh, const f16* __restrict__ Wph,
    const float* __restrict__ bp, float* __restrict__ out) {
    __shared__ __align__(16) f16 Ah[2][128 * 32];
    __shared__ __align__(16) f16 Bh[2][128 * 32];
    const int tid = threadIdx.x;
    const int l = tid & 63, w = tid >> 6;
    const int lo = l & 15, hi = l >> 4;
    const int wm = w >> 1, wn = w & 1;
    const int m0 = blockIdx.y * 128, o0 = blockIdx.x * 128;

    f32x4 acc[4][4];
#pragma unroll
    for (int i = 0; i < 4; ++i)
#pragma unroll
        for (int j = 0; j < 4; ++j) { f32x4 z = {0.f, 0.f, 0.f, 0.f}; acc[i][j] = z; }

    const int gr = l >> 2;
    const int gc = (l & 3) * 8;
    const f16* gA = Oh + (size_t)(m0 + w * 32 + gr) * DIM + gc;
    const f16* gB = Wph + (size_t)(o0 + w * 32 + gr) * DIM + gc;
    const int lofs = (w * 2) * 512;

    gload16(gA,            Ah[0] + lofs);
    gload16(gA + 16 * DIM, Ah[0] + lofs + 512);
    gload16(gB,            Bh[0] + lofs);
    gload16(gB + 16 * DIM, Bh[0] + lofs + 512);
    __syncthreads();

    int cur = 0;
    for (int k0 = 0; k0 < DIM; k0 += 32) {
        if (k0 + 32 < DIM) {
            gload16(gA + k0 + 32,            Ah[cur ^ 1] + lofs);
            gload16(gA + k0 + 32 + 16 * DIM, Ah[cur ^ 1] + lofs + 512);
            gload16(gB + k0 + 32,            Bh[cur ^ 1] + lofs);
            gload16(gB + k0 + 32 + 16 * DIM, Bh[cur ^ 1] + lofs + 512);
        }
        f16x8 af[4], bf[4];
#pragma unroll
        for (int i = 0; i < 4; ++i)
            af[i] = *(const f16x8*)&Ah[cur][(wm * 64 + i * 16 + lo) * 32 + hi * 8];
#pragma unroll
        for (int j = 0; j < 4; ++j)
            bf[j] = *(const f16x8*)&Bh[cur][(wn * 64 + j * 16 + lo) * 32 + hi * 8];
#pragma unroll
        for (int i = 0; i < 4; ++i)
#pragma unroll
            for (int j = 0; j < 4; ++j)
                acc[i][j] = __builtin_amdgcn_mfma_f32_16x16x32_f16(af[i], bf[j], acc[i][j], 0, 0, 0);
        __syncthreads();
        cur ^= 1;
    }

    float bpv[4];
#pragma unroll
    for (int j = 0; j < 4; ++j) bpv[j] = bp[o0 + wn * 64 + j * 16 + lo];
#pragma unroll
    for (int i = 0; i < 4; ++i)
#pragma unroll
        for (int r = 0; r < 4; ++r) {
            const int m = m0 + wm * 64 + i * 16 + hi * 4 + r;
#pragma unroll
            for (int j = 0; j < 4; ++j)
                out[(size_t)m * DIM + o0 + wn * 64 + j * 16 + lo] = acc[i][j][r] + bpv[j];
        }
}

// ---------------------------------------------------------------------------
extern "C" void kernel_launch(void* const* d_in, const int* in_sizes, int n_in,
                              void* d_out, int out_size, void* d_ws, size_t ws_size,
                              hipStream_t stream) {
    const float* x      = (const float*)d_in[0];
    const void*  mask   = d_in[1];
    const float* w_qkv  = (const float*)d_in[2];
    const float* w_proj = (const float*)d_in[3];
    const float* b_proj = (const float*)d_in[4];
    float* out          = (float*)d_out;

    char* w = (char*)d_ws;
    float* Mb = (float*)w;                 w += 16384;
    const size_t NX  = (size_t)NB * SEQ * DIM;
    const size_t NW1 = (size_t)3 * DIM * DIM;
    const size_t NW2 = (size_t)DIM * DIM;
    f16* Xh   = (f16*)w;  w += NX  * sizeof(f16);
    f16* W1h  = (f16*)w;  w += NW1 * sizeof(f16);
    f16* W2h  = (f16*)w;  w += NW2 * sizeof(f16);
    f16* Qh   = (f16*)w;  w += NX * sizeof(f16);
    f16* Kh   = (f16*)w;  w += NX * sizeof(f16);
    f16* Vth  = (f16*)w;  w += NX * sizeof(f16);
    f16* Oh   = (f16*)w;  w += NX * sizeof(f16);

    const int cvt_blocks = ((NB * SEQ * DIM + 4 * DIM * DIM) / 4 + 255) / 256 + 1;
    cvt_mask_kernel<<<cvt_blocks, 256, 0, stream>>>(x, w_qkv, w_proj, mask,
                                                    Xh, W1h, W2h, Mb);
    qkv_gemm_f16<<<dim3(18, 32), 256, 0, stream>>>(Xh, W1h, Qh, Kh, Vth);
    attn_f16<<<dim3(SEQ / 64, NBH), 256, 0, stream>>>(Qh, Kh, Vth, Mb, Oh);
    proj_gemm_f16<<<dim3(6, 32), 256, 0, stream>>>(Oh, W2h, b_proj, out);
}